// Round 2
// baseline (190.322 us; speedup 1.0000x reference)
//
#include <hip/hip_runtime.h>

// Attention: B=256,H=16,NQ=NK=49,D=64, fp32 in/out.
// R6 = persistent 4-head blocks + depth-2 global->reg prefetch pipeline.
// Theory: R5 showed dur_us flat under occupancy 42->65% with ALL counters far
// from roof => limiter is load-issue duty cycle (hipcc drains vmcnt(0) at
// __syncthreads, so no load survives a block's barrier; blocks convoy).
// Fix: loads for head i+1 issued before the barriers of head i and held in
// registers; barriers are LDS-only (s_waitcnt lgkmcnt(0) + raw s_barrier),
// never draining vmcnt. LDS K/Vt double-buffered (36.9 KB, 4 blocks/CU).
// Kept from R5: ST=72 stride, XOR-swizzled Vt transpose with UNCONDITIONAL
// zero-fill pad rows, no-max softmax, masked pad cols, P aliases K buffer
// behind the mid-barrier, Q straight to registers (scale folded in).

#define NQA 49
#define DD  64
#define ST  72   // LDS row stride (bf16 elems); 144 B keeps b128 reads aligned.
#define HPB 4    // heads per block

typedef __bf16 bf16x4 __attribute__((ext_vector_type(4)));
typedef __bf16 bf16x8 __attribute__((ext_vector_type(8)));
typedef float  f32x4  __attribute__((ext_vector_type(4)));

// Swizzled Vt offset for logical (d, k): k's group-of-8 rotated by (d>>2)&7.
__device__ __forceinline__ int vt_off(int d, int k) {
    return d * ST + ((((k >> 3) + ((d >> 2) & 7)) & 7) << 3) + (k & 7);
}

// LDS-only barrier: waits for this wave's outstanding LDS ops, then syncs.
// Crucially does NOT drain vmcnt -> prefetch loads stay in flight across it.
__device__ __forceinline__ void lds_barrier() {
    asm volatile("s_waitcnt lgkmcnt(0)" ::: "memory");
    __builtin_amdgcn_s_barrier();
}

struct Pref {
    float4 kr[4], vr[4];     // K,V rows (staging layout)
    float4 qa, qb, qc, qd;   // this wave's Q fragment slice
};

__device__ __forceinline__ void issue_loads(const float* __restrict__ Q,
                                            const float* __restrict__ K,
                                            const float* __restrict__ V,
                                            size_t head, int f, int r0,
                                            int w, int lr, int lg, Pref& p) {
    const size_t base = head * (size_t)(NQA * DD);
    const float* Kg = K + base;
    const float* Vg = V + base;
    #pragma unroll
    for (int it = 0; it < 4; ++it) {
        const int r = r0 + 16 * it;
        p.kr[it] = float4{0.f, 0.f, 0.f, 0.f};
        p.vr[it] = float4{0.f, 0.f, 0.f, 0.f};
        if (r < NQA) {
            p.kr[it] = *(const float4*)(Kg + r * DD + 4 * f);
            p.vr[it] = *(const float4*)(Vg + r * DD + 4 * f);
        }
    }
    const int qrow = 16 * w + lr;
    p.qa = p.qb = p.qc = p.qd = float4{0.f, 0.f, 0.f, 0.f};
    if (qrow < NQA) {
        const float* Qr = Q + base + (size_t)qrow * DD + 8 * lg;
        p.qa = *(const float4*)(Qr + 0);
        p.qb = *(const float4*)(Qr + 4);
        p.qc = *(const float4*)(Qr + 32);
        p.qd = *(const float4*)(Qr + 36);
    }
}

// Consume prefetch regs: convert to bf16, write K rows + swizzled Vt
// (UNCONDITIONAL so pad rows k=49..63 stay zero), build Q frags.
__device__ __forceinline__ void stage(const Pref& p, __bf16* Ksb, __bf16* Vtb,
                                      int f, int r0, bf16x8& aq0, bf16x8& aq1) {
    #pragma unroll
    for (int it = 0; it < 4; ++it) {
        const int r = r0 + 16 * it;
        bf16x4 kb = { (__bf16)p.kr[it].x, (__bf16)p.kr[it].y,
                      (__bf16)p.kr[it].z, (__bf16)p.kr[it].w };
        *(bf16x4*)&Ksb[r * ST + 4 * f] = kb;
        Vtb[vt_off(4*f + 0, r)] = (__bf16)p.vr[it].x;
        Vtb[vt_off(4*f + 1, r)] = (__bf16)p.vr[it].y;
        Vtb[vt_off(4*f + 2, r)] = (__bf16)p.vr[it].z;
        Vtb[vt_off(4*f + 3, r)] = (__bf16)p.vr[it].w;
    }
    // scale 1/sqrt(64) folded into the bf16 convert
    aq0 = bf16x8{ (__bf16)(0.125f*p.qa.x), (__bf16)(0.125f*p.qa.y),
                  (__bf16)(0.125f*p.qa.z), (__bf16)(0.125f*p.qa.w),
                  (__bf16)(0.125f*p.qb.x), (__bf16)(0.125f*p.qb.y),
                  (__bf16)(0.125f*p.qb.z), (__bf16)(0.125f*p.qb.w) };
    aq1 = bf16x8{ (__bf16)(0.125f*p.qc.x), (__bf16)(0.125f*p.qc.y),
                  (__bf16)(0.125f*p.qc.z), (__bf16)(0.125f*p.qc.w),
                  (__bf16)(0.125f*p.qd.x), (__bf16)(0.125f*p.qd.y),
                  (__bf16)(0.125f*p.qd.z), (__bf16)(0.125f*p.qd.w) };
}

__device__ __forceinline__ void compute_head(float* __restrict__ O, size_t head,
                                             __bf16* Ksb, const __bf16* Vtb,
                                             bf16x8 aq0, bf16x8 aq1,
                                             int w, int lr, int lg) {
    // ---- phase 1: S = (Q*scale) K^T ----
    f32x4 acc[4] = {};
    #pragma unroll
    for (int t = 0; t < 4; ++t) {
        bf16x8 b0 = *(const bf16x8*)&Ksb[(16*t + lr) * ST      + 8*lg];
        bf16x8 b1 = *(const bf16x8*)&Ksb[(16*t + lr) * ST + 32 + 8*lg];
        acc[t] = __builtin_amdgcn_mfma_f32_16x16x32_bf16(aq0, b0, acc[t], 0, 0, 0);
        acc[t] = __builtin_amdgcn_mfma_f32_16x16x32_bf16(aq1, b1, acc[t], 0, 0, 0);
    }

    lds_barrier();   // all waves done reading K frags before P overwrites

    // ---- softmax (no max-subtract; s bounded). Lane: rows 16w+4lg+i,
    //      col 16t+lr. K pad rows are zero => mask cols 49..63.
    float inv_l[4];
    #pragma unroll
    for (int i = 0; i < 4; ++i) {
        const int gq = 16*w + 4*lg + i;
        float e0 = __expf(acc[0][i]);
        float e1 = __expf(acc[1][i]);
        float e2 = __expf(acc[2][i]);
        float e3 = (lr == 0) ? __expf(acc[3][i]) : 0.f;  // cols 49..63 masked
        float sum = (e0 + e1) + (e2 + e3);
        #pragma unroll
        for (int d = 1; d < 16; d <<= 1) sum += __shfl_xor(sum, d, 64);
        inv_l[i] = 1.f / (sum + 1e-9f);
        // P rows are wave-private (alias onto Ksb; this wave re-reads only
        // its own 16 rows, which it fully rewrites here)
        Ksb[gq * ST +  0 + lr] = (__bf16)e0;
        Ksb[gq * ST + 16 + lr] = (__bf16)e1;
        Ksb[gq * ST + 32 + lr] = (__bf16)e2;
        Ksb[gq * ST + 48 + lr] = (__bf16)e3;
    }

    // ---- phase 2: O = P * V (B-frags from swizzled Vt, contiguous b128) ----
    bf16x8 ap0 = *(const bf16x8*)&Ksb[(16*w + lr) * ST      + 8*lg];
    bf16x8 ap1 = *(const bf16x8*)&Ksb[(16*w + lr) * ST + 32 + 8*lg];
    f32x4 oacc[4] = {};
    #pragma unroll
    for (int t = 0; t < 4; ++t) {
        bf16x8 b0 = *(const bf16x8*)&Vtb[vt_off(16*t + lr,  8*lg)];
        bf16x8 b1 = *(const bf16x8*)&Vtb[vt_off(16*t + lr, 32 + 8*lg)];
        oacc[t] = __builtin_amdgcn_mfma_f32_16x16x32_bf16(ap0, b0, oacc[t], 0, 0, 0);
        oacc[t] = __builtin_amdgcn_mfma_f32_16x16x32_bf16(ap1, b1, oacc[t], 0, 0, 0);
    }

    // ---- epilogue: scale by 1/(l+eps), store fp32 (fire-and-forget) ----
    float* Og = O + head * (size_t)(NQA * DD);
    #pragma unroll
    for (int i = 0; i < 4; ++i) {
        const int gq = 16*w + 4*lg + i;
        if (gq < NQA) {
            #pragma unroll
            for (int t = 0; t < 4; ++t)
                Og[gq * DD + 16*t + lr] = oacc[t][i] * inv_l[i];
        }
    }
}

__global__ __launch_bounds__(256, 4)
void attn49_kernel(const float* __restrict__ Q, const float* __restrict__ K,
                   const float* __restrict__ V, float* __restrict__ O) {
    __shared__ __bf16 Ks[2][64 * ST];   // K rows, then P rows (per head)
    __shared__ __bf16 Vt[2][64 * ST];   // swizzled V^T

    const int tid = threadIdx.x;
    const int f  = tid & 15;        // staging: float4 index within a row
    const int r0 = tid >> 4;        // staging: row group 0..15
    const int w  = tid >> 6;        // wave 0..3 owns S/O rows 16w..16w+15
    const int lr = tid & 15;
    const int lg = (tid >> 4) & 3;  // quad

    const size_t h0 = (size_t)blockIdx.x * HPB;

    Pref p;
    bf16x8 aqA0, aqA1, aqB0, aqB1;

    // ---- prologue: stage head 0, issue head 1 ----
    issue_loads(Q, K, V, h0 + 0, f, r0, w, lr, lg, p);
    stage(p, Ks[0], Vt[0], f, r0, aqA0, aqA1);
    issue_loads(Q, K, V, h0 + 1, f, r0, w, lr, lg, p);
    lds_barrier();

    // ---- iter 0: compute h0 | h1 loads in flight ----
    compute_head(O, h0 + 0, Ks[0], Vt[0], aqA0, aqA1, w, lr, lg);
    stage(p, Ks[1], Vt[1], f, r0, aqB0, aqB1);       // consume h1 regs
    issue_loads(Q, K, V, h0 + 2, f, r0, w, lr, lg, p); // h2 in flight
    lds_barrier();

    // ---- iter 1: compute h1 | h2 loads in flight ----
    compute_head(O, h0 + 1, Ks[1], Vt[1], aqB0, aqB1, w, lr, lg);
    stage(p, Ks[0], Vt[0], f, r0, aqA0, aqA1);       // consume h2 regs
    issue_loads(Q, K, V, h0 + 3, f, r0, w, lr, lg, p); // h3 in flight
    lds_barrier();

    // ---- iter 2: compute h2 | h3 loads in flight ----
    compute_head(O, h0 + 2, Ks[0], Vt[0], aqA0, aqA1, w, lr, lg);
    stage(p, Ks[1], Vt[1], f, r0, aqB0, aqB1);       // consume h3 regs
    lds_barrier();

    // ---- iter 3: compute h3 ----
    compute_head(O, h0 + 3, Ks[1], Vt[1], aqB0, aqB1, w, lr, lg);
}

extern "C" void kernel_launch(void* const* d_in, const int* in_sizes, int n_in,
                              void* d_out, int out_size, void* d_ws, size_t ws_size,
                              hipStream_t stream) {
    const float* q = (const float*)d_in[0];
    const float* k = (const float*)d_in[1];
    const float* v = (const float*)d_in[2];
    float* out = (float*)d_out;
    (void)in_sizes; (void)n_in; (void)out_size; (void)d_ws; (void)ws_size;
    attn49_kernel<<<dim3(4096 / HPB), dim3(256), 0, stream>>>(q, k, v, out);
}

// Round 4
// 187.988 us; speedup vs baseline: 1.0124x; 1.0124x over previous
//
#include <hip/hip_runtime.h>

// Attention: B=256,H=16,NQ=NK=49,D=64, fp32 in/out.
// R8 = R7 with the register budget fixed. R7 post-mortem: __launch_bounds__
// (256,4) = 128-VGPR cap while pinning 48 asm-output VGPRs + acc/oacc/frags
// (~160+ live) across the compute phase -> guaranteed spill of asm-pending
// registers (garbage) or RA failure on the asm constraints; bench died before
// running. R8 relaxes to __launch_bounds__(256,2) (<=256 VGPR, no spill).
//
// Pipeline (the actual experiment, now executable): loads for head i+1 are
// issued via asm volatile global_load_dwordx4 (cannot be sunk by LLVM) a full
// head before their vmcnt(0) consumption point; barriers are LDS-only
// (s_waitcnt lgkmcnt(0) + raw s_barrier) and never drain vmcnt, so the
// prefetch stays in flight under head i's MFMA/softmax. stage(i+1) sits
// BEFORE head i's epilogue stores, so its vmcnt(0) waits only on year-old
// ops. All prefetch loads are address-clamped & unconditional (uniform
// per-wave vmem counts); only vmcnt(0) is used (predicated epilogue stores
// make counted-N waits per-wave-nonuniform -> silent garbage).
// V pad rows zeroed post-load (0*garbage = NaN rule); K pad cols masked in
// softmax; Q pad rows never stored.
// Kept: ST=72 anti-conflict stride, XOR-swizzled Vt transpose, no-max
// softmax, P aliases K buffer behind the mid-barrier, grid 1024 x HPB=4.

#define NQA 49
#define DD  64
#define ST  72   // LDS row stride (bf16 elems); 144 B keeps b128 reads aligned.
#define HPB 4    // heads per block
#define BUF (64 * ST)

typedef __bf16 bf16x4 __attribute__((ext_vector_type(4)));
typedef __bf16 bf16x8 __attribute__((ext_vector_type(8)));
typedef float  f32x4  __attribute__((ext_vector_type(4)));

// Swizzled Vt offset for logical (d, k): k's group-of-8 rotated by (d>>2)&7.
__device__ __forceinline__ int vt_off(int d, int k) {
    return d * ST + ((((k >> 3) + ((d >> 2) & 7)) & 7) << 3) + (k & 7);
}

// LDS-only barrier: waits this wave's LDS ops, then raw s_barrier.
// Does NOT drain vmcnt -> prefetch loads stay in flight across it.
__device__ __forceinline__ void lds_barrier() {
    asm volatile("s_waitcnt lgkmcnt(0)" ::: "memory");
    __builtin_amdgcn_s_barrier();
}

// Forced async load: issued at this program point, result NOT waited on.
// LLVM believes the output is ready immediately; we own the vmcnt wait.
__device__ __forceinline__ float4 async_load(const float* p) {
    float4 d;
    asm volatile("global_load_dwordx4 %0, %1, off"
                 : "=v"(d) : "v"(p) : "memory");
    return d;
}

struct Pref {
    float4 kr[4], vr[4];     // K,V staging rows
    float4 q0, q1, q2, q3;   // this wave's Q fragment slice
};

__device__ __forceinline__ void issue_loads(const float* __restrict__ Q,
                                            const float* __restrict__ K,
                                            const float* __restrict__ V,
                                            size_t head, int f, int r0,
                                            int w, int lr, int lg, Pref& p) {
    const size_t base = head * (size_t)(NQA * DD);
    const float* Kg = K + base;
    const float* Vg = V + base;
    #pragma unroll
    for (int it = 0; it < 4; ++it) {
        const int r  = r0 + 16 * it;
        const int rc = (r < NQA) ? r : (NQA - 1);   // clamp: stay in-bounds
        p.kr[it] = async_load(Kg + rc * DD + 4 * f);
        p.vr[it] = async_load(Vg + rc * DD + 4 * f);
    }
    const int qrow = 16 * w + lr;
    const int qc   = (qrow < NQA) ? qrow : 0;       // clamp; values unused
    const float* Qr = Q + base + (size_t)qc * DD + 8 * lg;
    p.q0 = async_load(Qr + 0);
    p.q1 = async_load(Qr + 4);
    p.q2 = async_load(Qr + 32);
    p.q3 = async_load(Qr + 36);
}

// Wait for prefetch, convert, write K rows + swizzled Vt, build Q frags.
__device__ __forceinline__ void stage(const Pref& p, __bf16* Ksb, __bf16* Vtb,
                                      int f, int r0, bf16x8& aq0, bf16x8& aq1) {
    asm volatile("s_waitcnt vmcnt(0)" ::: "memory");
    __builtin_amdgcn_sched_barrier(0);   // rule #18: nothing crosses the wait
    #pragma unroll
    for (int it = 0; it < 4; ++it) {
        const int r = r0 + 16 * it;
        float4 kv = p.kr[it];
        float4 vv = p.vr[it];
        if (r >= NQA) vv = float4{0.f, 0.f, 0.f, 0.f};  // V pad rows MUST be 0
        bf16x4 kb = { (__bf16)kv.x, (__bf16)kv.y, (__bf16)kv.z, (__bf16)kv.w };
        *(bf16x4*)&Ksb[r * ST + 4 * f] = kb;
        Vtb[vt_off(4*f + 0, r)] = (__bf16)vv.x;
        Vtb[vt_off(4*f + 1, r)] = (__bf16)vv.y;
        Vtb[vt_off(4*f + 2, r)] = (__bf16)vv.z;
        Vtb[vt_off(4*f + 3, r)] = (__bf16)vv.w;
    }
    // scale 1/sqrt(64) folded into the bf16 convert
    aq0 = bf16x8{ (__bf16)(0.125f*p.q0.x), (__bf16)(0.125f*p.q0.y),
                  (__bf16)(0.125f*p.q0.z), (__bf16)(0.125f*p.q0.w),
                  (__bf16)(0.125f*p.q1.x), (__bf16)(0.125f*p.q1.y),
                  (__bf16)(0.125f*p.q1.z), (__bf16)(0.125f*p.q1.w) };
    aq1 = bf16x8{ (__bf16)(0.125f*p.q2.x), (__bf16)(0.125f*p.q2.y),
                  (__bf16)(0.125f*p.q2.z), (__bf16)(0.125f*p.q2.w),
                  (__bf16)(0.125f*p.q3.x), (__bf16)(0.125f*p.q3.y),
                  (__bf16)(0.125f*p.q3.z), (__bf16)(0.125f*p.q3.w) };
}

__global__ __launch_bounds__(256, 2)
void attn49_kernel(const float* __restrict__ Q, const float* __restrict__ K,
                   const float* __restrict__ V, float* __restrict__ O) {
    __shared__ __bf16 Ks[2][BUF];   // K rows, then P rows (per head)
    __shared__ __bf16 Vt[2][BUF];   // swizzled V^T

    const int tid = threadIdx.x;
    const int f  = tid & 15;        // staging: float4 index within a row
    const int r0 = tid >> 4;        // staging: row group 0..15
    const int w  = tid >> 6;        // wave 0..3 owns S/O rows 16w..16w+15
    const int lr = tid & 15;
    const int lg = (tid >> 4) & 3;  // quad

    const size_t h0 = (size_t)blockIdx.x * HPB;

    Pref p;
    bf16x8 aq_cur0, aq_cur1, aq_nxt0, aq_nxt1;

    // ---- prologue: load+stage head 0, put head 1 in flight ----
    issue_loads(Q, K, V, h0 + 0, f, r0, w, lr, lg, p);
    stage(p, Ks[0], Vt[0], f, r0, aq_cur0, aq_cur1);   // vmcnt(0): head-0 loads
    issue_loads(Q, K, V, h0 + 1, f, r0, w, lr, lg, p);
    lds_barrier();

    #pragma unroll
    for (int i = 0; i < HPB; ++i) {
        __bf16* Kb  = &Ks[i & 1][0];
        __bf16* Vb  = &Vt[i & 1][0];
        __bf16* Kbn = &Ks[(i + 1) & 1][0];
        __bf16* Vbn = &Vt[(i + 1) & 1][0];

        // ---- phase 1: S = (Q*scale) K^T ----
        f32x4 acc[4] = {};
        #pragma unroll
        for (int t = 0; t < 4; ++t) {
            bf16x8 b0 = *(const bf16x8*)&Kb[(16*t + lr) * ST      + 8*lg];
            bf16x8 b1 = *(const bf16x8*)&Kb[(16*t + lr) * ST + 32 + 8*lg];
            acc[t] = __builtin_amdgcn_mfma_f32_16x16x32_bf16(aq_cur0, b0, acc[t], 0, 0, 0);
            acc[t] = __builtin_amdgcn_mfma_f32_16x16x32_bf16(aq_cur1, b1, acc[t], 0, 0, 0);
        }

        lds_barrier();   // all waves' K-frag reads retired before P overwrites

        // ---- softmax (no max-subtract; s bounded). Lane: rows 16w+4lg+ii,
        //      col 16t+lr. Pad cols 49..63 masked (e3 only at lr==0 = col 48).
        float inv_l[4];
        #pragma unroll
        for (int ii = 0; ii < 4; ++ii) {
            const int gq = 16*w + 4*lg + ii;
            float e0 = __expf(acc[0][ii]);
            float e1 = __expf(acc[1][ii]);
            float e2 = __expf(acc[2][ii]);
            float e3 = (lr == 0) ? __expf(acc[3][ii]) : 0.f;
            float sum = (e0 + e1) + (e2 + e3);
            #pragma unroll
            for (int d = 1; d < 16; d <<= 1) sum += __shfl_xor(sum, d, 64);
            inv_l[ii] = 1.f / (sum + 1e-9f);
            // P rows are wave-private (alias onto Kb)
            Kb[gq * ST +  0 + lr] = (__bf16)e0;
            Kb[gq * ST + 16 + lr] = (__bf16)e1;
            Kb[gq * ST + 32 + lr] = (__bf16)e2;
            Kb[gq * ST + 48 + lr] = (__bf16)e3;
        }

        // ---- phase 2: O = P * V ----
        bf16x8 ap0 = *(const bf16x8*)&Kb[(16*w + lr) * ST      + 8*lg];
        bf16x8 ap1 = *(const bf16x8*)&Kb[(16*w + lr) * ST + 32 + 8*lg];
        f32x4 oacc[4] = {};
        #pragma unroll
        for (int t = 0; t < 4; ++t) {
            bf16x8 b0 = *(const bf16x8*)&Vb[vt_off(16*t + lr,  8*lg)];
            bf16x8 b1 = *(const bf16x8*)&Vb[vt_off(16*t + lr, 32 + 8*lg)];
            oacc[t] = __builtin_amdgcn_mfma_f32_16x16x32_bf16(ap0, b0, oacc[t], 0, 0, 0);
            oacc[t] = __builtin_amdgcn_mfma_f32_16x16x32_bf16(ap1, b1, oacc[t], 0, 0, 0);
        }

        // ---- stage next head BEFORE this head's stores: at the vmcnt(0)
        //      inside stage, outstanding vmem = next-head loads (issued a
        //      full head ago) + head i-1 stores (ancient) -> no stall.
        if (i + 1 < HPB) {
            stage(p, Kbn, Vbn, f, r0, aq_nxt0, aq_nxt1);
            if (i + 2 < HPB)
                issue_loads(Q, K, V, h0 + i + 2, f, r0, w, lr, lg, p);
        }

        // ---- epilogue: scale by 1/(l+eps), store fp32 (fire-and-forget) ----
        float* Og = O + (h0 + i) * (size_t)(NQA * DD);
        #pragma unroll
        for (int ii = 0; ii < 4; ++ii) {
            const int gq = 16*w + 4*lg + ii;
            if (gq < NQA) {
                #pragma unroll
                for (int t = 0; t < 4; ++t)
                    Og[gq * DD + 16*t + lr] = oacc[t][ii] * inv_l[ii];
            }
        }

        if (i + 1 < HPB) {
            lds_barrier();     // next buffer staged by all waves
            aq_cur0 = aq_nxt0;
            aq_cur1 = aq_nxt1;
        }
    }
}

extern "C" void kernel_launch(void* const* d_in, const int* in_sizes, int n_in,
                              void* d_out, int out_size, void* d_ws, size_t ws_size,
                              hipStream_t stream) {
    const float* q = (const float*)d_in[0];
    const float* k = (const float*)d_in[1];
    const float* v = (const float*)d_in[2];
    float* out = (float*)d_out;
    (void)in_sizes; (void)n_in; (void)out_size; (void)d_ws; (void)ws_size;
    attn49_kernel<<<dim3(4096 / HPB), dim3(256), 0, stream>>>(q, k, v, out);
}

// Round 5
// 186.151 us; speedup vs baseline: 1.0224x; 1.0099x over previous
//
#include <hip/hip_runtime.h>

// Attention: B=256,H=16,NQ=NK=49,D=64, fp32 in/out. One block per (b,h).
// R9 = barrier-free "waveflash". R5-R8 post-mortem: dur_us invariant at
// 71-77us across occupancy 23-65% with all pipes <25% busy => blocks convoy
// at their barriers (load-burst / sleep / compute phase-locking); three
// attempts to hold prefetch across barriers failed (compiler sinks plain
// loads; spills asm outputs at VGPR=68). Fix: remove ALL barriers.
//  - K,Q fragments loaded DIRECTLY from global in MFMA layout (lane lr reads
//    row 16t+lr, 16B chunks; lines fully consumed across half-frag pairs).
//  - V B-fragments via 8 scalar loads/lane (64-B segments, each V byte read
//    exactly once per head). K re-read 4x/head but from L1/L2 (25KB/head).
//  - P round-trip through WAVE-PRIVATE LDS (16x72 bf16 per wave): own-wave
//    RAW needs no barrier (compiler inserts lgkmcnt waits).
//  - Zero s_barrier => waves free-run at different phases; TLP hides latency.
// Numerics identical to proven kernel: bf16 MFMA, Q*0.125 at convert, no-max
// softmax (s bounded), pad cols 49..63 masked (e3 only at lr==0), pad-row
// loads address-clamped (finite garbage * P=0 = 0; garbage q-rows never
// stored). Fragment<->lane mappings unchanged from the proven kernel.

#define NQA 49
#define DD  64
#define PST 72   // P row stride (bf16): 144B -> b128 reads 2-way conflict (free)

typedef __bf16 bf16x8 __attribute__((ext_vector_type(8)));
typedef float  f32x4  __attribute__((ext_vector_type(4)));

__global__ __launch_bounds__(256, 4)
void attn49_kernel(const float* __restrict__ Q, const float* __restrict__ K,
                   const float* __restrict__ V, float* __restrict__ O) {
    __shared__ __bf16 P[4][16 * PST];   // wave-private P tiles (9216 B total)

    const int tid = threadIdx.x;
    const int w  = tid >> 6;        // wave 0..3 owns q-rows 16w..16w+15
    const int lr = tid & 15;
    const int lg = (tid >> 4) & 3;  // quad

    const size_t base = (size_t)blockIdx.x * (NQA * DD);
    const float* Qg = Q + base;
    const float* Kg = K + base;
    const float* Vg = V + base;

    // ---- Q A-frags straight from global (row clamped; pad rows never stored)
    bf16x8 aq0, aq1;
    {
        const int qrow = 16*w + lr;
        const int qc   = (qrow < NQA) ? qrow : (NQA - 1);
        const float* Qr = Qg + qc * DD + 8 * lg;
        float4 a = *(const float4*)(Qr + 0);
        float4 b = *(const float4*)(Qr + 4);
        float4 c = *(const float4*)(Qr + 32);
        float4 d = *(const float4*)(Qr + 36);
        // scale 1/sqrt(64) folded into the bf16 convert
        aq0 = bf16x8{ (__bf16)(0.125f*a.x), (__bf16)(0.125f*a.y),
                      (__bf16)(0.125f*a.z), (__bf16)(0.125f*a.w),
                      (__bf16)(0.125f*b.x), (__bf16)(0.125f*b.y),
                      (__bf16)(0.125f*b.z), (__bf16)(0.125f*b.w) };
        aq1 = bf16x8{ (__bf16)(0.125f*c.x), (__bf16)(0.125f*c.y),
                      (__bf16)(0.125f*c.z), (__bf16)(0.125f*c.w),
                      (__bf16)(0.125f*d.x), (__bf16)(0.125f*d.y),
                      (__bf16)(0.125f*d.z), (__bf16)(0.125f*d.w) };
    }

    // ---- phase 1: S = (Q*scale) K^T, B-frags direct from global ----
    // b-frag layout (proven): lane (lr,lg) holds K[16t+lr][8lg+j] (j=0..7)
    f32x4 acc[4] = {};
    #pragma unroll
    for (int t = 0; t < 4; ++t) {
        const int kr = 16*t + lr;
        const int kc = (kr < NQA) ? kr : (NQA - 1);   // dup row 48; masked below
        const float* Kr = Kg + kc * DD + 8 * lg;
        float4 a = *(const float4*)(Kr + 0);
        float4 b = *(const float4*)(Kr + 4);
        float4 c = *(const float4*)(Kr + 32);
        float4 d = *(const float4*)(Kr + 36);
        bf16x8 kb0 = { (__bf16)a.x, (__bf16)a.y, (__bf16)a.z, (__bf16)a.w,
                       (__bf16)b.x, (__bf16)b.y, (__bf16)b.z, (__bf16)b.w };
        bf16x8 kb1 = { (__bf16)c.x, (__bf16)c.y, (__bf16)c.z, (__bf16)c.w,
                       (__bf16)d.x, (__bf16)d.y, (__bf16)d.z, (__bf16)d.w };
        acc[t] = __builtin_amdgcn_mfma_f32_16x16x32_bf16(aq0, kb0, acc[t], 0, 0, 0);
        acc[t] = __builtin_amdgcn_mfma_f32_16x16x32_bf16(aq1, kb1, acc[t], 0, 0, 0);
    }

    // ---- softmax (no max-subtract; s bounded). Lane: rows 16w+4lg+ii,
    //      col 16t+lr. Pad cols 49..63 masked (e3 only at lr==0 = col 48).
    __bf16* Pw = &P[w][0];
    float inv_l[4];
    #pragma unroll
    for (int ii = 0; ii < 4; ++ii) {
        float e0 = __expf(acc[0][ii]);
        float e1 = __expf(acc[1][ii]);
        float e2 = __expf(acc[2][ii]);
        float e3 = (lr == 0) ? __expf(acc[3][ii]) : 0.f;
        float sum = (e0 + e1) + (e2 + e3);
        #pragma unroll
        for (int d = 1; d < 16; d <<= 1) sum += __shfl_xor(sum, d, 64);
        inv_l[ii] = 1.f / (sum + 1e-9f);
        const int pr = 4*lg + ii;            // row within this wave's P tile
        Pw[pr * PST +  0 + lr] = (__bf16)e0;
        Pw[pr * PST + 16 + lr] = (__bf16)e1;
        Pw[pr * PST + 32 + lr] = (__bf16)e2;
        Pw[pr * PST + 48 + lr] = (__bf16)e3;  // cols 49..63 = 0
    }

    // ---- P A-frags from wave-private LDS (no barrier: own-wave RAW) ----
    bf16x8 ap0 = *(const bf16x8*)&Pw[lr * PST      + 8*lg];
    bf16x8 ap1 = *(const bf16x8*)&Pw[lr * PST + 32 + 8*lg];

    // ---- phase 2: O = P * V, V B-frags via direct scalar loads ----
    // b-frag: lane (lr,lg) holds V[32h+8lg+j][16t+lr]. Row offsets shared
    // across t; statically indexed (fully unrolled) so they stay in VGPRs.
    int voff[16];
    #pragma unroll
    for (int u = 0; u < 16; ++u) {
        const int vr = 32 * (u >> 3) + 8 * lg + (u & 7);
        voff[u] = ((vr < NQA) ? vr : (NQA - 1)) * DD;  // dup row 48; P=0 there
    }
    f32x4 oacc[4] = {};
    #pragma unroll
    for (int t = 0; t < 4; ++t) {
        const float* Vc = Vg + 16*t + lr;   // column base for this d-tile
        #pragma unroll
        for (int h = 0; h < 2; ++h) {
            bf16x8 vb;
            #pragma unroll
            for (int j = 0; j < 8; ++j)
                vb[j] = (__bf16)Vc[voff[8*h + j]];
            oacc[t] = __builtin_amdgcn_mfma_f32_16x16x32_bf16(
                          h ? ap1 : ap0, vb, oacc[t], 0, 0, 0);
        }
    }

    // ---- epilogue: scale by 1/(l+eps), store fp32 (64-B segments) ----
    float* Og = O + base;
    #pragma unroll
    for (int ii = 0; ii < 4; ++ii) {
        const int gq = 16*w + 4*lg + ii;
        if (gq < NQA) {
            #pragma unroll
            for (int t = 0; t < 4; ++t)
                Og[gq * DD + 16*t + lr] = oacc[t][ii] * inv_l[ii];
        }
    }
}

extern "C" void kernel_launch(void* const* d_in, const int* in_sizes, int n_in,
                              void* d_out, int out_size, void* d_ws, size_t ws_size,
                              hipStream_t stream) {
    const float* q = (const float*)d_in[0];
    const float* k = (const float*)d_in[1];
    const float* v = (const float*)d_in[2];
    float* out = (float*)d_out;
    (void)in_sizes; (void)n_in; (void)out_size; (void)d_ws; (void)ws_size;
    attn49_kernel<<<dim3(4096), dim3(256), 0, stream>>>(q, k, v, out);
}

// Round 6
// 183.849 us; speedup vs baseline: 1.0352x; 1.0125x over previous
//
#include <hip/hip_runtime.h>

// Attention: B=256,H=16,NQ=NK=49,D=64, fp32 in/out. One block per (b,h).
// R10 = R9 (barrier-free) + sched_barrier(0) region fencing to force
// memory-level parallelism. R9 post-mortem: VGPR=48 proves the compiler sank
// all global loads to their use sites (register-minimizing), so each wave
// held ~1-2 loads in flight -> latency*concurrency bound at ~1.8 TB/s. This
// unified model fits R4-R9 (barriers drained vmcnt in R4-R8; sinking
// serialized R9). Fix: partition into scheduling regions with
// __builtin_amdgcn_sched_barrier(0):
//   [issue Q + 16 K float4] | [phase-1 MFMA] | [issue 64 V dwords]
//   | [softmax + P LDS roundtrip] | [phase-2 MFMA + store]
// Loads issue a full region before use; V latency hides under softmax.
// Compiler still owns the (counted) waitcnts on these plain loads.
// Kept from R9 (passed, absmax 0.015625): direct-from-global K/Q frags,
// scalar-column V frags, wave-private P tile in LDS (no barrier for own-wave
// RAW), no-max softmax, pad col masking, address clamps, zero s_barrier.

#define NQA 49
#define DD  64
#define PST 72   // P row stride (bf16): 144B -> b128 reads 2-way conflict (free)

typedef __bf16 bf16x8 __attribute__((ext_vector_type(8)));
typedef float  f32x4  __attribute__((ext_vector_type(4)));

__global__ __launch_bounds__(256, 4)
void attn49_kernel(const float* __restrict__ Q, const float* __restrict__ K,
                   const float* __restrict__ V, float* __restrict__ O) {
    __shared__ __bf16 P[4][16 * PST];   // wave-private P tiles (9216 B total)

    const int tid = threadIdx.x;
    const int w  = tid >> 6;        // wave 0..3 owns q-rows 16w..16w+15
    const int lr = tid & 15;
    const int lg = (tid >> 4) & 3;  // quad

    const size_t base = (size_t)blockIdx.x * (NQA * DD);
    const float* Qg = Q + base;
    const float* Kg = K + base;
    const float* Vg = V + base;

    // ================= region 1: issue Q + all K loads =================
    float4 qv[4];
    {
        const int qrow = 16*w + lr;
        const int qc   = (qrow < NQA) ? qrow : (NQA - 1);
        const float* Qr = Qg + qc * DD + 8 * lg;
        qv[0] = *(const float4*)(Qr + 0);
        qv[1] = *(const float4*)(Qr + 4);
        qv[2] = *(const float4*)(Qr + 32);
        qv[3] = *(const float4*)(Qr + 36);
    }
    float4 kf[16];
    #pragma unroll
    for (int t = 0; t < 4; ++t) {
        const int kr = 16*t + lr;
        const int kc = (kr < NQA) ? kr : (NQA - 1);   // dup row 48; masked below
        const float* Kr = Kg + kc * DD + 8 * lg;
        kf[4*t + 0] = *(const float4*)(Kr + 0);
        kf[4*t + 1] = *(const float4*)(Kr + 4);
        kf[4*t + 2] = *(const float4*)(Kr + 32);
        kf[4*t + 3] = *(const float4*)(Kr + 36);
    }
    __builtin_amdgcn_sched_barrier(0);

    // ================= region 2: phase-1 MFMA =========================
    bf16x8 aq0 = { (__bf16)(0.125f*qv[0].x), (__bf16)(0.125f*qv[0].y),
                   (__bf16)(0.125f*qv[0].z), (__bf16)(0.125f*qv[0].w),
                   (__bf16)(0.125f*qv[1].x), (__bf16)(0.125f*qv[1].y),
                   (__bf16)(0.125f*qv[1].z), (__bf16)(0.125f*qv[1].w) };
    bf16x8 aq1 = { (__bf16)(0.125f*qv[2].x), (__bf16)(0.125f*qv[2].y),
                   (__bf16)(0.125f*qv[2].z), (__bf16)(0.125f*qv[2].w),
                   (__bf16)(0.125f*qv[3].x), (__bf16)(0.125f*qv[3].y),
                   (__bf16)(0.125f*qv[3].z), (__bf16)(0.125f*qv[3].w) };
    f32x4 acc[4] = {};
    #pragma unroll
    for (int t = 0; t < 4; ++t) {
        float4 a = kf[4*t + 0], b = kf[4*t + 1],
               c = kf[4*t + 2], d = kf[4*t + 3];
        bf16x8 kb0 = { (__bf16)a.x, (__bf16)a.y, (__bf16)a.z, (__bf16)a.w,
                       (__bf16)b.x, (__bf16)b.y, (__bf16)b.z, (__bf16)b.w };
        bf16x8 kb1 = { (__bf16)c.x, (__bf16)c.y, (__bf16)c.z, (__bf16)c.w,
                       (__bf16)d.x, (__bf16)d.y, (__bf16)d.z, (__bf16)d.w };
        acc[t] = __builtin_amdgcn_mfma_f32_16x16x32_bf16(aq0, kb0, acc[t], 0, 0, 0);
        acc[t] = __builtin_amdgcn_mfma_f32_16x16x32_bf16(aq1, kb1, acc[t], 0, 0, 0);
    }
    __builtin_amdgcn_sched_barrier(0);

    // ================= region 3: issue all 64 V loads =================
    // lane (lr,lg) needs V[8lg+j+32h][16t+lr]; rows clamped to <=48 (the
    // clamped duplicates multiply P=0 pad cols -> contribute nothing).
    float vf[64];
    #pragma unroll
    for (int t = 0; t < 4; ++t) {
        const float* Vc = Vg + 16*t + lr;
        #pragma unroll
        for (int h = 0; h < 2; ++h) {
            #pragma unroll
            for (int j = 0; j < 8; ++j) {
                const int vr = 32*h + 8*lg + j;
                const int vc = (vr < NQA) ? vr : (NQA - 1);
                vf[16*t + 8*h + j] = Vc[vc * DD];
            }
        }
    }
    __builtin_amdgcn_sched_barrier(0);

    // ================= region 4: softmax + P roundtrip ================
    // Lane: rows 16w+4lg+ii, col 16t+lr. Pad cols 49..63 masked (e3 only
    // at lr==0 = col 48). V latency hides under this region.
    __bf16* Pw = &P[w][0];
    float inv_l[4];
    #pragma unroll
    for (int ii = 0; ii < 4; ++ii) {
        float e0 = __expf(acc[0][ii]);
        float e1 = __expf(acc[1][ii]);
        float e2 = __expf(acc[2][ii]);
        float e3 = (lr == 0) ? __expf(acc[3][ii]) : 0.f;
        float sum = (e0 + e1) + (e2 + e3);
        #pragma unroll
        for (int d = 1; d < 16; d <<= 1) sum += __shfl_xor(sum, d, 64);
        inv_l[ii] = 1.f / (sum + 1e-9f);
        const int pr = 4*lg + ii;            // row within this wave's P tile
        Pw[pr * PST +  0 + lr] = (__bf16)e0;
        Pw[pr * PST + 16 + lr] = (__bf16)e1;
        Pw[pr * PST + 32 + lr] = (__bf16)e2;
        Pw[pr * PST + 48 + lr] = (__bf16)e3;  // cols 49..63 = 0
    }
    // P A-frags from wave-private LDS (no barrier: own-wave RAW; compiler
    // inserts the lgkmcnt wait).
    bf16x8 ap0 = *(const bf16x8*)&Pw[lr * PST      + 8*lg];
    bf16x8 ap1 = *(const bf16x8*)&Pw[lr * PST + 32 + 8*lg];

    // ================= region 5: phase-2 MFMA + store =================
    f32x4 oacc[4] = {};
    #pragma unroll
    for (int t = 0; t < 4; ++t) {
        #pragma unroll
        for (int h = 0; h < 2; ++h) {
            bf16x8 vb;
            #pragma unroll
            for (int j = 0; j < 8; ++j)
                vb[j] = (__bf16)vf[16*t + 8*h + j];
            oacc[t] = __builtin_amdgcn_mfma_f32_16x16x32_bf16(
                          h ? ap1 : ap0, vb, oacc[t], 0, 0, 0);
        }
    }

    float* Og = O + base;
    #pragma unroll
    for (int ii = 0; ii < 4; ++ii) {
        const int gq = 16*w + 4*lg + ii;
        if (gq < NQA) {
            #pragma unroll
            for (int t = 0; t < 4; ++t)
                Og[gq * DD + 16*t + lr] = oacc[t][ii] * inv_l[ii];
        }
    }
}

extern "C" void kernel_launch(void* const* d_in, const int* in_sizes, int n_in,
                              void* d_out, int out_size, void* d_ws, size_t ws_size,
                              hipStream_t stream) {
    const float* q = (const float*)d_in[0];
    const float* k = (const float*)d_in[1];
    const float* v = (const float*)d_in[2];
    float* out = (float*)d_out;
    (void)in_sizes; (void)n_in; (void)out_size; (void)d_ws; (void)ws_size;
    attn49_kernel<<<dim3(4096), dim3(256), 0, stream>>>(q, k, v, out);
}